// Round 19
// baseline (141.511 us; speedup 1.0000x reference)
//
#include <hip/hip_runtime.h>
#include <math.h>

#define DD 64
#define CSCALE 16384.0f   // 2^14 exact scale for codebook
#define SBIAS 4096.0f     // additive bias -> all scores positive floats
#define BIGF 3.402823466e+38f
#define TILEB 16384       // packed tile bytes per kt (8KB hi + 8KB lo)
#define RTK 128           // refine: codes per LDS tile
#define RPAD 68           // refine: floats per LDS row (64 + 4 pad)

typedef float f32x64 __attribute__((ext_vector_type(64)));
typedef float f32x4  __attribute__((ext_vector_type(4)));
typedef _Float16 half8 __attribute__((ext_vector_type(8)));

__device__ __forceinline__ unsigned med3u(unsigned a, unsigned b, unsigned c) {
    unsigned d;
    asm("v_med3_u32 %0, %1, %2, %3" : "=v"(d) : "v"(a), "v"(b), "v"(c));
    return d;
}

// ---- np-bit-exact znorm / row-norm (verified rounds 1-18) ----
__device__ __forceinline__ float znorm64(const f32x64& vz) {
    float r0 = __fmul_rn(vz[0], vz[0]);
    float r1 = __fmul_rn(vz[1], vz[1]);
    float r2 = __fmul_rn(vz[2], vz[2]);
    float r3 = __fmul_rn(vz[3], vz[3]);
    float r4 = __fmul_rn(vz[4], vz[4]);
    float r5 = __fmul_rn(vz[5], vz[5]);
    float r6 = __fmul_rn(vz[6], vz[6]);
    float r7 = __fmul_rn(vz[7], vz[7]);
#pragma unroll
    for (int i = 8; i < DD; i += 8) {
        r0 = __fadd_rn(r0, __fmul_rn(vz[i + 0], vz[i + 0]));
        r1 = __fadd_rn(r1, __fmul_rn(vz[i + 1], vz[i + 1]));
        r2 = __fadd_rn(r2, __fmul_rn(vz[i + 2], vz[i + 2]));
        r3 = __fadd_rn(r3, __fmul_rn(vz[i + 3], vz[i + 3]));
        r4 = __fadd_rn(r4, __fmul_rn(vz[i + 4], vz[i + 4]));
        r5 = __fadd_rn(r5, __fmul_rn(vz[i + 5], vz[i + 5]));
        r6 = __fadd_rn(r6, __fmul_rn(vz[i + 6], vz[i + 6]));
        r7 = __fadd_rn(r7, __fmul_rn(vz[i + 7], vz[i + 7]));
    }
    float a = __fadd_rn(r0, r1);
    float b = __fadd_rn(r2, r3);
    float c = __fadd_rn(r4, r5);
    float e = __fadd_rn(r6, r7);
    return __fadd_rn(__fadd_rn(a, b), __fadd_rn(c, e));
}

__device__ __forceinline__ void loadpt(const float* __restrict__ p, f32x64& v) {
    const float4* p4 = reinterpret_cast<const float4*>(p);
#pragma unroll
    for (int i = 0; i < DD / 4; ++i) {
        float4 t = p4[i];
        v[4 * i + 0] = t.x;
        v[4 * i + 1] = t.y;
        v[4 * i + 2] = t.z;
        v[4 * i + 3] = t.w;
    }
}

// two-term fp16 split: hi = fp16(s*x), lo = fp16(s*x - hi)
__device__ __forceinline__ void cvt8s(float4 a, float4 b, float s, half8& hi, half8& lo) {
    float v;
#define ONE(i, comp) v = s * comp; { _Float16 h_ = (_Float16)v; hi[i] = h_; lo[i] = (_Float16)(v - (float)h_); }
    ONE(0, a.x) ONE(1, a.y) ONE(2, a.z) ONE(3, a.w)
    ONE(4, b.x) ONE(5, b.y) ONE(6, b.z) ONE(7, b.w)
#undef ONE
}

__device__ __forceinline__ float sq16(float4 f0, float4 f1, float4 g0, float4 g1) {
    return f0.x*f0.x + f0.y*f0.y + f0.z*f0.z + f0.w*f0.w
         + f1.x*f1.x + f1.y*f1.y + f1.z*f1.z + f1.w*f1.w
         + g0.x*g0.x + g0.y*g0.y + g0.z*g0.z + g0.w*g0.w
         + g1.x*g1.x + g1.y*g1.y + g1.z*g1.z + g1.w*g1.w;
}

// ------- kernel PC: pack codebook (fp16 hi/lo swizzled image) + cnorms -------
// (verified round 18, unchanged)
__global__ __launch_bounds__(256) void packc_kernel(const float* __restrict__ cb,
                                                    unsigned char* __restrict__ pack,
                                                    float* __restrict__ cnorm,
                                                    float* __restrict__ cnsb,
                                                    unsigned* __restrict__ maxcn, int K) {
    int u = blockIdx.x * 256 + threadIdx.x;
    if (u < 8192) {
        int kt = u >> 9;
        int c = (u >> 3) & 63;
        int sub = u & 7;
        const float* src = cb + ((size_t)(kt * 64 + c)) * DD + sub * 8;
        float4 u0 = *(const float4*)src;
        float4 u1 = *(const float4*)(src + 4);
        half8 h, l;
        cvt8s(u0, u1, CSCALE, h, l);
        int byte = (c * 128 + sub * 16) ^ ((c & 7) << 4);
        *(half8*)(pack + (size_t)kt * TILEB + byte) = h;
        *(half8*)(pack + (size_t)kt * TILEB + 8192 + byte) = l;
    }
    if (u < K) {
        const float* row = cb + (size_t)u * DD;
        float r0 = __fmul_rn(row[0], row[0]);
        float r1 = __fmul_rn(row[1], row[1]);
        float r2 = __fmul_rn(row[2], row[2]);
        float r3 = __fmul_rn(row[3], row[3]);
        float r4 = __fmul_rn(row[4], row[4]);
        float r5 = __fmul_rn(row[5], row[5]);
        float r6 = __fmul_rn(row[6], row[6]);
        float r7 = __fmul_rn(row[7], row[7]);
#pragma unroll
        for (int i = 8; i < DD; i += 8) {
            r0 = __fadd_rn(r0, __fmul_rn(row[i + 0], row[i + 0]));
            r1 = __fadd_rn(r1, __fmul_rn(row[i + 1], row[i + 1]));
            r2 = __fadd_rn(r2, __fmul_rn(row[i + 2], row[i + 2]));
            r3 = __fadd_rn(r3, __fmul_rn(row[i + 3], row[i + 3]));
            r4 = __fadd_rn(r4, __fmul_rn(row[i + 4], row[i + 4]));
            r5 = __fadd_rn(r5, __fmul_rn(row[i + 5], row[i + 5]));
            r6 = __fadd_rn(r6, __fmul_rn(row[i + 6], row[i + 6]));
            r7 = __fadd_rn(r7, __fmul_rn(row[i + 7], row[i + 7]));
        }
        float a = __fadd_rn(r0, r1);
        float b = __fadd_rn(r2, r3);
        float c = __fadd_rn(r4, r5);
        float e = __fadd_rn(r6, r7);
        float v = __fadd_rn(__fadd_rn(a, b), __fadd_rn(c, e));
        cnorm[u] = v;
        cnsb[u] = __builtin_fmaf(CSCALE, v, SBIAS);
        atomicMax(maxcn, __float_as_uint(v));
    }
}

// ------------- kernel M: split-fp16 MFMA scoring, packed-uint top-2 ----------
// R18 datapath verbatim; geometry change only: 256-thread blocks (4 waves,
// 128 points), grid = N/128 = 1024, __launch_bounds__(256,4) (VGPR cap 128,
// no spill -- R16's failure was the LB(256,5)=48-VGPR spill, not the shape).
// 4 independent blocks/CU interleave across barriers (no 8-wave lockstep) and
// finer quanta reduce tail idle.
__global__ __launch_bounds__(256, 4) void mfma_argmin_kernel(
        const float* __restrict__ z, const unsigned char* __restrict__ pack,
        const float* __restrict__ cnsb, const unsigned* __restrict__ maxcn,
        float* __restrict__ outIdxF, unsigned* __restrict__ cnt,
        unsigned* __restrict__ list, int N, int K) {
    __shared__ __align__(16) unsigned char lds[2 * TILEB];   // 32 KB double buffer

    const int tid = threadIdx.x;
    const int lane = tid & 63;
    const int wave = tid >> 6;          // 0..3
    const int cls = lane & 15;
    const int grp = lane >> 4;
    const int ptA = blockIdx.x * 128 + wave * 32;
    const int ptB = ptA + 16;

    half8 aA0h, aA0l, aA1h, aA1l, aB0h, aB0l, aB1h, aB1l;
    float znA, znB;
    {
        const float* p = z + (size_t)(ptA + cls) * DD + grp * 8;
        float4 f0 = *(const float4*)p;
        float4 f1 = *(const float4*)(p + 4);
        float4 g0 = *(const float4*)(p + 32);
        float4 g1 = *(const float4*)(p + 36);
        cvt8s(f0, f1, -2.0f, aA0h, aA0l);
        cvt8s(g0, g1, -2.0f, aA1h, aA1l);
        znA = sq16(f0, f1, g0, g1);
    }
    {
        const float* p = z + (size_t)(ptB + cls) * DD + grp * 8;
        float4 f0 = *(const float4*)p;
        float4 f1 = *(const float4*)(p + 4);
        float4 g0 = *(const float4*)(p + 32);
        float4 g1 = *(const float4*)(p + 36);
        cvt8s(f0, f1, -2.0f, aB0h, aB0l);
        cvt8s(g0, g1, -2.0f, aB1h, aB1l);
        znB = sq16(f0, f1, g0, g1);
    }
    znA += __shfl_xor(znA, 16); znA += __shfl_xor(znA, 32);
    znB += __shfl_xor(znB, 16); znB += __shfl_xor(znB, 32);

    uint4 m1A = {~0u, ~0u, ~0u, ~0u}, m2A = m1A;
    uint4 m1B = m1A, m2B = m1A;

    {   // prologue: stage tile 0 (1024 float4, 4 per thread)
        const float4* gp = (const float4*)pack;
        float4* l4 = (float4*)lds;
        l4[tid] = gp[tid];
        l4[tid + 256] = gp[tid + 256];
        l4[tid + 512] = gp[tid + 512];
        l4[tid + 768] = gp[tid + 768];
    }
    __syncthreads();

    const int nKT = K / 64;   // 16
#pragma unroll 2
    for (int kt = 0; kt < nKT; ++kt) {
        const int p = kt & 1;
        float4 s0, s1, s2, s3;
        const bool pf = (kt + 1 < nKT);
        if (pf) {   // issue-early
            const float4* gn = (const float4*)(pack + (size_t)(kt + 1) * TILEB);
            s0 = gn[tid];
            s1 = gn[tid + 256];
            s2 = gn[tid + 512];
            s3 = gn[tid + 768];
        }

        const unsigned char* bb = lds + p * TILEB;
#pragma unroll
        for (int ct = 0; ct < 4; ++ct) {
            const int cl = ct * 16 + cls;
            const int sw = (cl & 7) << 4;
            const int o0 = (cl * 128 + grp * 16) ^ sw;
            const int o1 = (cl * 128 + 64 + grp * 16) ^ sw;
            const half8 b0h = *(const half8*)(bb + o0);
            const half8 b1h = *(const half8*)(bb + o1);
            const half8 b0l = *(const half8*)(bb + 8192 + o0);
            const half8 b1l = *(const half8*)(bb + 8192 + o1);
            const float cnv = cnsb[kt * 64 + cl];
            const unsigned id = (unsigned)(kt * 4 + ct);   // 6-bit

            f32x4 pa = {cnv, cnv, cnv, cnv};
            pa = __builtin_amdgcn_mfma_f32_16x16x32_f16(aA0l, b0h, pa, 0, 0, 0);
            pa = __builtin_amdgcn_mfma_f32_16x16x32_f16(aA0h, b0l, pa, 0, 0, 0);
            pa = __builtin_amdgcn_mfma_f32_16x16x32_f16(aA0h, b0h, pa, 0, 0, 0);
            f32x4 qa = {0.f, 0.f, 0.f, 0.f};
            qa = __builtin_amdgcn_mfma_f32_16x16x32_f16(aA1l, b1h, qa, 0, 0, 0);
            qa = __builtin_amdgcn_mfma_f32_16x16x32_f16(aA1h, b1l, qa, 0, 0, 0);
            qa = __builtin_amdgcn_mfma_f32_16x16x32_f16(aA1h, b1h, qa, 0, 0, 0);
            f32x4 sA = pa + qa;

            f32x4 pb = {cnv, cnv, cnv, cnv};
            pb = __builtin_amdgcn_mfma_f32_16x16x32_f16(aB0l, b0h, pb, 0, 0, 0);
            pb = __builtin_amdgcn_mfma_f32_16x16x32_f16(aB0h, b0l, pb, 0, 0, 0);
            pb = __builtin_amdgcn_mfma_f32_16x16x32_f16(aB0h, b0h, pb, 0, 0, 0);
            f32x4 qb = {0.f, 0.f, 0.f, 0.f};
            qb = __builtin_amdgcn_mfma_f32_16x16x32_f16(aB1l, b1h, qb, 0, 0, 0);
            qb = __builtin_amdgcn_mfma_f32_16x16x32_f16(aB1h, b1l, qb, 0, 0, 0);
            qb = __builtin_amdgcn_mfma_f32_16x16x32_f16(aB1h, b1h, qb, 0, 0, 0);
            f32x4 sB = pb + qb;

#define TRK(M1, M2, V) { unsigned ky_ = (__float_as_uint(V) & ~63u) | id; \
            M2 = med3u(M1, M2, ky_); M1 = (ky_ < M1) ? ky_ : M1; }
            TRK(m1A.x, m2A.x, sA[0]) TRK(m1A.y, m2A.y, sA[1])
            TRK(m1A.z, m2A.z, sA[2]) TRK(m1A.w, m2A.w, sA[3])
            TRK(m1B.x, m2B.x, sB[0]) TRK(m1B.y, m2B.y, sB[1])
            TRK(m1B.z, m2B.z, sB[2]) TRK(m1B.w, m2B.w, sB[3])
#undef TRK
        }

        if (pf) {   // write-late
            float4* d4 = (float4*)(lds + (1 - p) * TILEB);
            d4[tid] = s0;
            d4[tid + 256] = s1;
            d4[tid + 512] = s2;
            d4[tid + 768] = s3;
        }
        __syncthreads();
    }

    // ---- cross-lane top-2 merge over 16 code classes, carrying cls ----
    uint4 cwA = {(unsigned)cls, (unsigned)cls, (unsigned)cls, (unsigned)cls};
    uint4 cwB = cwA;
#define MRG1(M1, M2, CW, XO) { \
    unsigned o1_ = (unsigned)__shfl_xor((int)(M1), XO); \
    unsigned o2_ = (unsigned)__shfl_xor((int)(M2), XO); \
    unsigned oc_ = (unsigned)__shfl_xor((int)(CW), XO); \
    unsigned mx_ = ((M1) > o1_) ? (M1) : o1_; \
    unsigned n2_ = ((M2) < o2_) ? (M2) : o2_; \
    n2_ = (n2_ < mx_) ? n2_ : mx_; \
    bool tk_ = (o1_ < (M1)) || (o1_ == (M1) && oc_ < (CW)); \
    CW = tk_ ? oc_ : (CW); \
    M1 = (o1_ < (M1)) ? o1_ : (M1); \
    M2 = n2_; }
#define MRG4(T, XO) MRG1(m1##T.x, m2##T.x, cw##T.x, XO) \
                    MRG1(m1##T.y, m2##T.y, cw##T.y, XO) \
                    MRG1(m1##T.z, m2##T.z, cw##T.z, XO) \
                    MRG1(m1##T.w, m2##T.w, cw##T.w, XO)
    MRG4(A, 1) MRG4(A, 2) MRG4(A, 4) MRG4(A, 8)
    MRG4(B, 1) MRG4(B, 2) MRG4(B, 4) MRG4(B, 8)
#undef MRG4
#undef MRG1

    // znorm of rows this lane will emit (shfl pre-branch: all lanes active)
    const int row0 = (grp << 2);
    float zA0 = __shfl(znA, row0 + 0), zA1 = __shfl(znA, row0 + 1);
    float zA2 = __shfl(znA, row0 + 2), zA3 = __shfl(znA, row0 + 3);
    float zB0 = __shfl(znB, row0 + 0), zB1 = __shfl(znB, row0 + 1);
    float zB2 = __shfl(znB, row0 + 2), zB3 = __shfl(znB, row0 + 3);

    const float cnmax = __uint_as_float(*maxcn);
    const float sC = sqrtf(cnmax * 1.0001f);

    if (cls == 0) {
#define EMIT(PTBASE, R, ZNR, M1, M2, CW) { \
        float sz_ = sqrtf((ZNR) * 1.0001f); \
        float delta_ = CSCALE * (3.0e-7f * (ZNR) + 5.0e-5f * sz_ * sC + 1.0e-5f) + 0.12f; \
        bool safe_ = (CSCALE * (2.0f * sz_ * sC + cnmax) < 3800.0f); \
        float fm1_ = __uint_as_float((M1) & ~63u); \
        float fm2_ = __uint_as_float((M2) & ~63u); \
        int pt_ = (PTBASE) + row0 + (R); \
        if (safe_ && (fm2_ - fm1_ > delta_)) { \
            unsigned idb_ = (M1) & 63u; \
            outIdxF[pt_] = (float)((idb_ >> 2) * 64 + (idb_ & 3) * 16 + (CW)); \
        } else { unsigned pos_ = atomicAdd(cnt, 1u); list[pos_] = (unsigned)pt_; } }
        EMIT(ptA, 0, zA0, m1A.x, m2A.x, cwA.x)
        EMIT(ptA, 1, zA1, m1A.y, m2A.y, cwA.y)
        EMIT(ptA, 2, zA2, m1A.z, m2A.z, cwA.z)
        EMIT(ptA, 3, zA3, m1A.w, m2A.w, cwA.w)
        EMIT(ptB, 0, zB0, m1B.x, m2B.x, cwB.x)
        EMIT(ptB, 1, zB1, m1B.y, m2B.y, cwB.y)
        EMIT(ptB, 2, zB2, m1B.z, m2B.z, cwB.z)
        EMIT(ptB, 3, zB3, m1B.w, m2B.w, cwB.w)
#undef EMIT
    }
}

// ------- kernel R v3: np-bit-exact refine, LDS-staged, 16 pts/block ----------
// (verified round 11, unchanged)
__global__ __launch_bounds__(256, 2) void refine_kernel(
        const float* __restrict__ z, const float* __restrict__ cb,
        const float* __restrict__ cnorm, const unsigned* __restrict__ cnt,
        const unsigned* __restrict__ list, float* __restrict__ outIdxF, int K) {
    __shared__ float tile[RTK * RPAD];
    __shared__ float tcn[RTK];

    const unsigned count = *cnt;
    if (count == 0) return;
    const int tid = threadIdx.x;
    const int g = tid >> 4;
    const int gl = tid & 15;
    const unsigned nChunks = (count + 15u) >> 4;

    for (unsigned chunk = blockIdx.x; chunk < nChunks; chunk += gridDim.x) {
        const unsigned gidx = (chunk << 4) + (unsigned)g;
        const bool act = (gidx < count);
        const int pt = (int)list[act ? gidx : 0];

        f32x64 vz;
        loadpt(z + (size_t)pt * DD, vz);
        const float znorm = znorm64(vz);

        float best = BIGF;
        int bidx = 0x7fffffff;

        for (int t = 0; t < K / RTK; ++t) {
            __syncthreads();
            {
                const float4* src = reinterpret_cast<const float4*>(cb + (size_t)t * RTK * DD);
#pragma unroll
                for (int i = 0; i < 8; ++i) {
                    int f = tid + i * 256;
                    int row = f >> 4;
                    int c4 = f & 15;
                    *reinterpret_cast<float4*>(tile + row * RPAD + c4 * 4) = src[f];
                }
                if (tid < RTK) tcn[tid] = cnorm[t * RTK + tid];
            }
            __syncthreads();

#pragma unroll
            for (int tt = 0; tt < RTK / 16; ++tt) {
                const int ci = gl + 16 * tt;
                const float* crow = tile + ci * RPAD;
                float a0 = 0.0f;
#pragma unroll
                for (int i = 0; i < DD / 4; ++i) {
                    float4 x = *reinterpret_cast<const float4*>(crow + 4 * i);
                    a0 = __builtin_fmaf(vz[4 * i + 0], x.x, a0);
                    a0 = __builtin_fmaf(vz[4 * i + 1], x.y, a0);
                    a0 = __builtin_fmaf(vz[4 * i + 2], x.z, a0);
                    a0 = __builtin_fmaf(vz[4 * i + 3], x.w, a0);
                }
                float d = __fadd_rn(__builtin_fmaf(-2.0f, a0, znorm), tcn[ci]);
                int k = t * RTK + ci;
                if (d < best) { best = d; bidx = k; }
            }
        }

#pragma unroll
        for (int off = 1; off <= 8; off <<= 1) {
            float ob = __shfl_xor(best, off);
            int oi = __shfl_xor(bidx, off);
            if (ob < best || (ob == best && oi < bidx)) { best = ob; bidx = oi; }
        }
        if (act && gl == 0) outIdxF[pt] = (float)bidx;
    }
}

// ------------- kernel G: gather z_q, write z_q_st, loss partials -------------
__global__ __launch_bounds__(256) void gather_kernel(const float* __restrict__ z,
                                                     const float* __restrict__ cb,
                                                     const float* __restrict__ idxF,
                                                     float* __restrict__ out0,
                                                     float* __restrict__ partials,
                                                     int N) {
    int gtid = blockIdx.x * 256 + threadIdx.x;
    int wave = gtid >> 6;
    int lane = threadIdx.x & 63;
    int nwaves = (gridDim.x * 256) >> 6;

    float acc = 0.0f;
    for (int n = wave; n < N; n += nwaves) {
        int idx = (int)idxF[n];
        float q = cb[(size_t)idx * DD + lane];
        float zv = z[(size_t)n * DD + lane];
        float t = q - zv;
        out0[(size_t)n * DD + lane] = zv + t;
        acc += t * t;
    }
#pragma unroll
    for (int off = 32; off; off >>= 1) acc += __shfl_xor(acc, off);

    __shared__ float ws[4];
    if (lane == 0) ws[threadIdx.x >> 6] = acc;
    __syncthreads();
    if (threadIdx.x == 0) {
        float s = (ws[0] + ws[1]) + (ws[2] + ws[3]);
        partials[blockIdx.x] = s;
    }
}

// ---------------- kernel F: finalize loss ------------------------------------
__global__ __launch_bounds__(256) void finalize_kernel(const float* __restrict__ partials,
                                                       int nPart, float* __restrict__ lossOut,
                                                       float totalElems) {
    __shared__ float sh[256];
    float s = 0.0f;
    for (int i = threadIdx.x; i < nPart; i += 256) s += partials[i];
    sh[threadIdx.x] = s;
    __syncthreads();
    for (int stride = 128; stride; stride >>= 1) {
        if (threadIdx.x < stride) sh[threadIdx.x] += sh[threadIdx.x + stride];
        __syncthreads();
    }
    if (threadIdx.x == 0) {
        float m = sh[0] / totalElems;
        float p = 0.25f * m;
        lossOut[0] = __fadd_rn(p, m);
    }
}

extern "C" void kernel_launch(void* const* d_in, const int* in_sizes, int n_in,
                              void* d_out, int out_size, void* d_ws, size_t ws_size,
                              hipStream_t stream) {
    const float* z = (const float*)d_in[0];
    const float* cb = (const float*)d_in[1];
    const int N = in_sizes[0] / DD;   // 131072
    const int K = in_sizes[1] / DD;   // 1024

    float* out0 = (float*)d_out;                       // z_q_st
    float* lossOut = out0 + (size_t)N * DD;            // 1 float
    float* outIdxF = lossOut + 1;                      // N floats

    unsigned char* pack = (unsigned char*)d_ws;        // 256 KB
    unsigned* maxcn = (unsigned*)(pack + 16 * TILEB);  // [0]
    unsigned* cnt = maxcn + 1;                         // [1]
    float* cnorm = (float*)(maxcn + 2);                // K floats (np-exact)
    float* cnsb = cnorm + K;                           // K floats (biased-scaled)
    float* partials = cnsb + K;                        // 2048 floats
    unsigned* list = (unsigned*)(partials + 2048);     // N uints

    hipMemsetAsync(maxcn, 0, 8, stream);               // zero maxcn + cnt

    packc_kernel<<<32, 256, 0, stream>>>(cb, pack, cnorm, cnsb, maxcn, K);
    mfma_argmin_kernel<<<N / 128, 256, 0, stream>>>(z, pack, cnsb, maxcn,
                                                    outIdxF, cnt, list, N, K);
    refine_kernel<<<512, 256, 0, stream>>>(z, cb, cnorm, cnt, list, outIdxF, K);

    const int nBlocks2 = 2048;
    gather_kernel<<<nBlocks2, 256, 0, stream>>>(z, cb, outIdxF, out0, partials, N);
    finalize_kernel<<<1, 256, 0, stream>>>(partials, nBlocks2, lossOut,
                                           (float)((size_t)N * DD));
}

// Round 20
// 139.849 us; speedup vs baseline: 1.0119x; 1.0119x over previous
//
#include <hip/hip_runtime.h>
#include <math.h>

#define DD 64
#define CSCALE 16384.0f   // 2^14 exact scale for codebook
#define SBIAS 4096.0f     // additive bias -> all scores positive floats
#define BIGF 3.402823466e+38f
#define TILEB 16384       // packed tile bytes per kt (8KB hi + 8KB lo)
#define RTK 128           // refine: codes per LDS tile
#define RPAD 68           // refine: floats per LDS row (64 + 4 pad)

typedef float f32x64 __attribute__((ext_vector_type(64)));
typedef float f32x4  __attribute__((ext_vector_type(4)));
typedef _Float16 half8 __attribute__((ext_vector_type(8)));

__device__ __forceinline__ unsigned med3u(unsigned a, unsigned b, unsigned c) {
    unsigned d;
    asm("v_med3_u32 %0, %1, %2, %3" : "=v"(d) : "v"(a), "v"(b), "v"(c));
    return d;
}

// ---- np-bit-exact znorm / row-norm (verified rounds 1-19) ----
__device__ __forceinline__ float znorm64(const f32x64& vz) {
    float r0 = __fmul_rn(vz[0], vz[0]);
    float r1 = __fmul_rn(vz[1], vz[1]);
    float r2 = __fmul_rn(vz[2], vz[2]);
    float r3 = __fmul_rn(vz[3], vz[3]);
    float r4 = __fmul_rn(vz[4], vz[4]);
    float r5 = __fmul_rn(vz[5], vz[5]);
    float r6 = __fmul_rn(vz[6], vz[6]);
    float r7 = __fmul_rn(vz[7], vz[7]);
#pragma unroll
    for (int i = 8; i < DD; i += 8) {
        r0 = __fadd_rn(r0, __fmul_rn(vz[i + 0], vz[i + 0]));
        r1 = __fadd_rn(r1, __fmul_rn(vz[i + 1], vz[i + 1]));
        r2 = __fadd_rn(r2, __fmul_rn(vz[i + 2], vz[i + 2]));
        r3 = __fadd_rn(r3, __fmul_rn(vz[i + 3], vz[i + 3]));
        r4 = __fadd_rn(r4, __fmul_rn(vz[i + 4], vz[i + 4]));
        r5 = __fadd_rn(r5, __fmul_rn(vz[i + 5], vz[i + 5]));
        r6 = __fadd_rn(r6, __fmul_rn(vz[i + 6], vz[i + 6]));
        r7 = __fadd_rn(r7, __fmul_rn(vz[i + 7], vz[i + 7]));
    }
    float a = __fadd_rn(r0, r1);
    float b = __fadd_rn(r2, r3);
    float c = __fadd_rn(r4, r5);
    float e = __fadd_rn(r6, r7);
    return __fadd_rn(__fadd_rn(a, b), __fadd_rn(c, e));
}

__device__ __forceinline__ void loadpt(const float* __restrict__ p, f32x64& v) {
    const float4* p4 = reinterpret_cast<const float4*>(p);
#pragma unroll
    for (int i = 0; i < DD / 4; ++i) {
        float4 t = p4[i];
        v[4 * i + 0] = t.x;
        v[4 * i + 1] = t.y;
        v[4 * i + 2] = t.z;
        v[4 * i + 3] = t.w;
    }
}

// two-term fp16 split: hi = fp16(s*x), lo = fp16(s*x - hi)
__device__ __forceinline__ void cvt8s(float4 a, float4 b, float s, half8& hi, half8& lo) {
    float v;
#define ONE(i, comp) v = s * comp; { _Float16 h_ = (_Float16)v; hi[i] = h_; lo[i] = (_Float16)(v - (float)h_); }
    ONE(0, a.x) ONE(1, a.y) ONE(2, a.z) ONE(3, a.w)
    ONE(4, b.x) ONE(5, b.y) ONE(6, b.z) ONE(7, b.w)
#undef ONE
}

__device__ __forceinline__ float sq16(float4 f0, float4 f1, float4 g0, float4 g1) {
    return f0.x*f0.x + f0.y*f0.y + f0.z*f0.z + f0.w*f0.w
         + f1.x*f1.x + f1.y*f1.y + f1.z*f1.z + f1.w*f1.w
         + g0.x*g0.x + g0.y*g0.y + g0.z*g0.z + g0.w*g0.w
         + g1.x*g1.x + g1.y*g1.y + g1.z*g1.z + g1.w*g1.w;
}

// ------- kernel PC: pack codebook (fp16 hi/lo swizzled image) + cnorms -------
__global__ __launch_bounds__(256) void packc_kernel(const float* __restrict__ cb,
                                                    unsigned char* __restrict__ pack,
                                                    float* __restrict__ cnorm,
                                                    float* __restrict__ cnsb,
                                                    unsigned* __restrict__ maxcn, int K) {
    int u = blockIdx.x * 256 + threadIdx.x;
    if (u < 8192) {
        int kt = u >> 9;
        int c = (u >> 3) & 63;
        int sub = u & 7;
        const float* src = cb + ((size_t)(kt * 64 + c)) * DD + sub * 8;
        float4 u0 = *(const float4*)src;
        float4 u1 = *(const float4*)(src + 4);
        half8 h, l;
        cvt8s(u0, u1, CSCALE, h, l);
        int byte = (c * 128 + sub * 16) ^ ((c & 7) << 4);
        *(half8*)(pack + (size_t)kt * TILEB + byte) = h;
        *(half8*)(pack + (size_t)kt * TILEB + 8192 + byte) = l;
    }
    if (u < K) {
        const float* row = cb + (size_t)u * DD;
        float r0 = __fmul_rn(row[0], row[0]);
        float r1 = __fmul_rn(row[1], row[1]);
        float r2 = __fmul_rn(row[2], row[2]);
        float r3 = __fmul_rn(row[3], row[3]);
        float r4 = __fmul_rn(row[4], row[4]);
        float r5 = __fmul_rn(row[5], row[5]);
        float r6 = __fmul_rn(row[6], row[6]);
        float r7 = __fmul_rn(row[7], row[7]);
#pragma unroll
        for (int i = 8; i < DD; i += 8) {
            r0 = __fadd_rn(r0, __fmul_rn(row[i + 0], row[i + 0]));
            r1 = __fadd_rn(r1, __fmul_rn(row[i + 1], row[i + 1]));
            r2 = __fadd_rn(r2, __fmul_rn(row[i + 2], row[i + 2]));
            r3 = __fadd_rn(r3, __fmul_rn(row[i + 3], row[i + 3]));
            r4 = __fadd_rn(r4, __fmul_rn(row[i + 4], row[i + 4]));
            r5 = __fadd_rn(r5, __fmul_rn(row[i + 5], row[i + 5]));
            r6 = __fadd_rn(r6, __fmul_rn(row[i + 6], row[i + 6]));
            r7 = __fadd_rn(r7, __fmul_rn(row[i + 7], row[i + 7]));
        }
        float a = __fadd_rn(r0, r1);
        float b = __fadd_rn(r2, r3);
        float c = __fadd_rn(r4, r5);
        float e = __fadd_rn(r6, r7);
        float v = __fadd_rn(__fadd_rn(a, b), __fadd_rn(c, e));
        cnorm[u] = v;
        cnsb[u] = __builtin_fmaf(CSCALE, v, SBIAS);
        atomicMax(maxcn, __float_as_uint(v));
    }
}

// ------------- kernel M: split-fp16 MFMA scoring, packed-uint top-2 ----------
// Best-measured configuration (R18 = 139.9us total, M = 76.5us): 512 threads,
// 2 point-tiles/wave, full-K scan, double-buffered LDS with issue-early/
// write-late staging, two serial 3-deep MFMA chains per point-tile,
// 6-bit id key, cw-carry merge, inline gate+emit/flag.
__global__ __launch_bounds__(512, 4) void mfma_argmin_kernel(
        const float* __restrict__ z, const unsigned char* __restrict__ pack,
        const float* __restrict__ cnsb, const unsigned* __restrict__ maxcn,
        float* __restrict__ outIdxF, unsigned* __restrict__ cnt,
        unsigned* __restrict__ list, int N, int K) {
    __shared__ __align__(16) unsigned char lds[2 * TILEB];   // 32 KB double buffer

    const int tid = threadIdx.x;
    const int lane = tid & 63;
    const int wave = tid >> 6;
    const int cls = lane & 15;
    const int grp = lane >> 4;
    const int ptA = blockIdx.x * 256 + wave * 32;
    const int ptB = ptA + 16;

    half8 aA0h, aA0l, aA1h, aA1l, aB0h, aB0l, aB1h, aB1l;
    float znA, znB;
    {
        const float* p = z + (size_t)(ptA + cls) * DD + grp * 8;
        float4 f0 = *(const float4*)p;
        float4 f1 = *(const float4*)(p + 4);
        float4 g0 = *(const float4*)(p + 32);
        float4 g1 = *(const float4*)(p + 36);
        cvt8s(f0, f1, -2.0f, aA0h, aA0l);
        cvt8s(g0, g1, -2.0f, aA1h, aA1l);
        znA = sq16(f0, f1, g0, g1);
    }
    {
        const float* p = z + (size_t)(ptB + cls) * DD + grp * 8;
        float4 f0 = *(const float4*)p;
        float4 f1 = *(const float4*)(p + 4);
        float4 g0 = *(const float4*)(p + 32);
        float4 g1 = *(const float4*)(p + 36);
        cvt8s(f0, f1, -2.0f, aB0h, aB0l);
        cvt8s(g0, g1, -2.0f, aB1h, aB1l);
        znB = sq16(f0, f1, g0, g1);
    }
    znA += __shfl_xor(znA, 16); znA += __shfl_xor(znA, 32);
    znB += __shfl_xor(znB, 16); znB += __shfl_xor(znB, 32);

    uint4 m1A = {~0u, ~0u, ~0u, ~0u}, m2A = m1A;
    uint4 m1B = m1A, m2B = m1A;

    {   // prologue: stage tile 0
        const float4* gp = (const float4*)pack;
        float4* l4 = (float4*)lds;
        l4[tid] = gp[tid];
        l4[tid + 512] = gp[tid + 512];
    }
    __syncthreads();

    const int nKT = K / 64;   // 16
#pragma unroll 2
    for (int kt = 0; kt < nKT; ++kt) {
        const int p = kt & 1;
        float4 sa, sb;
        const bool pf = (kt + 1 < nKT);
        if (pf) {   // issue-early
            const float4* gn = (const float4*)(pack + (size_t)(kt + 1) * TILEB);
            sa = gn[tid];
            sb = gn[tid + 512];
        }

        const unsigned char* bb = lds + p * TILEB;
#pragma unroll
        for (int ct = 0; ct < 4; ++ct) {
            const int cl = ct * 16 + cls;
            const int sw = (cl & 7) << 4;
            const int o0 = (cl * 128 + grp * 16) ^ sw;
            const int o1 = (cl * 128 + 64 + grp * 16) ^ sw;
            const half8 b0h = *(const half8*)(bb + o0);
            const half8 b1h = *(const half8*)(bb + o1);
            const half8 b0l = *(const half8*)(bb + 8192 + o0);
            const half8 b1l = *(const half8*)(bb + 8192 + o1);
            const float cnv = cnsb[kt * 64 + cl];
            const unsigned id = (unsigned)(kt * 4 + ct);   // 6-bit

            f32x4 pa = {cnv, cnv, cnv, cnv};
            pa = __builtin_amdgcn_mfma_f32_16x16x32_f16(aA0l, b0h, pa, 0, 0, 0);
            pa = __builtin_amdgcn_mfma_f32_16x16x32_f16(aA0h, b0l, pa, 0, 0, 0);
            pa = __builtin_amdgcn_mfma_f32_16x16x32_f16(aA0h, b0h, pa, 0, 0, 0);
            f32x4 qa = {0.f, 0.f, 0.f, 0.f};
            qa = __builtin_amdgcn_mfma_f32_16x16x32_f16(aA1l, b1h, qa, 0, 0, 0);
            qa = __builtin_amdgcn_mfma_f32_16x16x32_f16(aA1h, b1l, qa, 0, 0, 0);
            qa = __builtin_amdgcn_mfma_f32_16x16x32_f16(aA1h, b1h, qa, 0, 0, 0);
            f32x4 sA = pa + qa;

            f32x4 pb = {cnv, cnv, cnv, cnv};
            pb = __builtin_amdgcn_mfma_f32_16x16x32_f16(aB0l, b0h, pb, 0, 0, 0);
            pb = __builtin_amdgcn_mfma_f32_16x16x32_f16(aB0h, b0l, pb, 0, 0, 0);
            pb = __builtin_amdgcn_mfma_f32_16x16x32_f16(aB0h, b0h, pb, 0, 0, 0);
            f32x4 qb = {0.f, 0.f, 0.f, 0.f};
            qb = __builtin_amdgcn_mfma_f32_16x16x32_f16(aB1l, b1h, qb, 0, 0, 0);
            qb = __builtin_amdgcn_mfma_f32_16x16x32_f16(aB1h, b1l, qb, 0, 0, 0);
            qb = __builtin_amdgcn_mfma_f32_16x16x32_f16(aB1h, b1h, qb, 0, 0, 0);
            f32x4 sB = pb + qb;

#define TRK(M1, M2, V) { unsigned ky_ = (__float_as_uint(V) & ~63u) | id; \
            M2 = med3u(M1, M2, ky_); M1 = (ky_ < M1) ? ky_ : M1; }
            TRK(m1A.x, m2A.x, sA[0]) TRK(m1A.y, m2A.y, sA[1])
            TRK(m1A.z, m2A.z, sA[2]) TRK(m1A.w, m2A.w, sA[3])
            TRK(m1B.x, m2B.x, sB[0]) TRK(m1B.y, m2B.y, sB[1])
            TRK(m1B.z, m2B.z, sB[2]) TRK(m1B.w, m2B.w, sB[3])
#undef TRK
        }

        if (pf) {   // write-late
            float4* d4 = (float4*)(lds + (1 - p) * TILEB);
            d4[tid] = sa;
            d4[tid + 512] = sb;
        }
        __syncthreads();
    }

    // ---- cross-lane top-2 merge over 16 code classes, carrying cls ----
    uint4 cwA = {(unsigned)cls, (unsigned)cls, (unsigned)cls, (unsigned)cls};
    uint4 cwB = cwA;
#define MRG1(M1, M2, CW, XO) { \
    unsigned o1_ = (unsigned)__shfl_xor((int)(M1), XO); \
    unsigned o2_ = (unsigned)__shfl_xor((int)(M2), XO); \
    unsigned oc_ = (unsigned)__shfl_xor((int)(CW), XO); \
    unsigned mx_ = ((M1) > o1_) ? (M1) : o1_; \
    unsigned n2_ = ((M2) < o2_) ? (M2) : o2_; \
    n2_ = (n2_ < mx_) ? n2_ : mx_; \
    bool tk_ = (o1_ < (M1)) || (o1_ == (M1) && oc_ < (CW)); \
    CW = tk_ ? oc_ : (CW); \
    M1 = (o1_ < (M1)) ? o1_ : (M1); \
    M2 = n2_; }
#define MRG4(T, XO) MRG1(m1##T.x, m2##T.x, cw##T.x, XO) \
                    MRG1(m1##T.y, m2##T.y, cw##T.y, XO) \
                    MRG1(m1##T.z, m2##T.z, cw##T.z, XO) \
                    MRG1(m1##T.w, m2##T.w, cw##T.w, XO)
    MRG4(A, 1) MRG4(A, 2) MRG4(A, 4) MRG4(A, 8)
    MRG4(B, 1) MRG4(B, 2) MRG4(B, 4) MRG4(B, 8)
#undef MRG4
#undef MRG1

    // znorm of rows this lane will emit (shfl pre-branch: all lanes active)
    const int row0 = (grp << 2);
    float zA0 = __shfl(znA, row0 + 0), zA1 = __shfl(znA, row0 + 1);
    float zA2 = __shfl(znA, row0 + 2), zA3 = __shfl(znA, row0 + 3);
    float zB0 = __shfl(znB, row0 + 0), zB1 = __shfl(znB, row0 + 1);
    float zB2 = __shfl(znB, row0 + 2), zB3 = __shfl(znB, row0 + 3);

    const float cnmax = __uint_as_float(*maxcn);
    const float sC = sqrtf(cnmax * 1.0001f);

    if (cls == 0) {
#define EMIT(PTBASE, R, ZNR, M1, M2, CW) { \
        float sz_ = sqrtf((ZNR) * 1.0001f); \
        float delta_ = CSCALE * (3.0e-7f * (ZNR) + 5.0e-5f * sz_ * sC + 1.0e-5f) + 0.12f; \
        bool safe_ = (CSCALE * (2.0f * sz_ * sC + cnmax) < 3800.0f); \
        float fm1_ = __uint_as_float((M1) & ~63u); \
        float fm2_ = __uint_as_float((M2) & ~63u); \
        int pt_ = (PTBASE) + row0 + (R); \
        if (safe_ && (fm2_ - fm1_ > delta_)) { \
            unsigned idb_ = (M1) & 63u; \
            outIdxF[pt_] = (float)((idb_ >> 2) * 64 + (idb_ & 3) * 16 + (CW)); \
        } else { unsigned pos_ = atomicAdd(cnt, 1u); list[pos_] = (unsigned)pt_; } }
        EMIT(ptA, 0, zA0, m1A.x, m2A.x, cwA.x)
        EMIT(ptA, 1, zA1, m1A.y, m2A.y, cwA.y)
        EMIT(ptA, 2, zA2, m1A.z, m2A.z, cwA.z)
        EMIT(ptA, 3, zA3, m1A.w, m2A.w, cwA.w)
        EMIT(ptB, 0, zB0, m1B.x, m2B.x, cwB.x)
        EMIT(ptB, 1, zB1, m1B.y, m2B.y, cwB.y)
        EMIT(ptB, 2, zB2, m1B.z, m2B.z, cwB.z)
        EMIT(ptB, 3, zB3, m1B.w, m2B.w, cwB.w)
#undef EMIT
    }
}

// ------- kernel R v3: np-bit-exact refine, LDS-staged, 16 pts/block ----------
// (verified round 11, unchanged)
__global__ __launch_bounds__(256, 2) void refine_kernel(
        const float* __restrict__ z, const float* __restrict__ cb,
        const float* __restrict__ cnorm, const unsigned* __restrict__ cnt,
        const unsigned* __restrict__ list, float* __restrict__ outIdxF, int K) {
    __shared__ float tile[RTK * RPAD];
    __shared__ float tcn[RTK];

    const unsigned count = *cnt;
    if (count == 0) return;
    const int tid = threadIdx.x;
    const int g = tid >> 4;
    const int gl = tid & 15;
    const unsigned nChunks = (count + 15u) >> 4;

    for (unsigned chunk = blockIdx.x; chunk < nChunks; chunk += gridDim.x) {
        const unsigned gidx = (chunk << 4) + (unsigned)g;
        const bool act = (gidx < count);
        const int pt = (int)list[act ? gidx : 0];

        f32x64 vz;
        loadpt(z + (size_t)pt * DD, vz);
        const float znorm = znorm64(vz);

        float best = BIGF;
        int bidx = 0x7fffffff;

        for (int t = 0; t < K / RTK; ++t) {
            __syncthreads();
            {
                const float4* src = reinterpret_cast<const float4*>(cb + (size_t)t * RTK * DD);
#pragma unroll
                for (int i = 0; i < 8; ++i) {
                    int f = tid + i * 256;
                    int row = f >> 4;
                    int c4 = f & 15;
                    *reinterpret_cast<float4*>(tile + row * RPAD + c4 * 4) = src[f];
                }
                if (tid < RTK) tcn[tid] = cnorm[t * RTK + tid];
            }
            __syncthreads();

#pragma unroll
            for (int tt = 0; tt < RTK / 16; ++tt) {
                const int ci = gl + 16 * tt;
                const float* crow = tile + ci * RPAD;
                float a0 = 0.0f;
#pragma unroll
                for (int i = 0; i < DD / 4; ++i) {
                    float4 x = *reinterpret_cast<const float4*>(crow + 4 * i);
                    a0 = __builtin_fmaf(vz[4 * i + 0], x.x, a0);
                    a0 = __builtin_fmaf(vz[4 * i + 1], x.y, a0);
                    a0 = __builtin_fmaf(vz[4 * i + 2], x.z, a0);
                    a0 = __builtin_fmaf(vz[4 * i + 3], x.w, a0);
                }
                float d = __fadd_rn(__builtin_fmaf(-2.0f, a0, znorm), tcn[ci]);
                int k = t * RTK + ci;
                if (d < best) { best = d; bidx = k; }
            }
        }

#pragma unroll
        for (int off = 1; off <= 8; off <<= 1) {
            float ob = __shfl_xor(best, off);
            int oi = __shfl_xor(bidx, off);
            if (ob < best || (ob == best && oi < bidx)) { best = ob; bidx = oi; }
        }
        if (act && gl == 0) outIdxF[pt] = (float)bidx;
    }
}

// ------------- kernel G: gather z_q, write z_q_st, loss partials -------------
__global__ __launch_bounds__(256) void gather_kernel(const float* __restrict__ z,
                                                     const float* __restrict__ cb,
                                                     const float* __restrict__ idxF,
                                                     float* __restrict__ out0,
                                                     float* __restrict__ partials,
                                                     int N) {
    int gtid = blockIdx.x * 256 + threadIdx.x;
    int wave = gtid >> 6;
    int lane = threadIdx.x & 63;
    int nwaves = (gridDim.x * 256) >> 6;

    float acc = 0.0f;
    for (int n = wave; n < N; n += nwaves) {
        int idx = (int)idxF[n];
        float q = cb[(size_t)idx * DD + lane];
        float zv = z[(size_t)n * DD + lane];
        float t = q - zv;
        out0[(size_t)n * DD + lane] = zv + t;
        acc += t * t;
    }
#pragma unroll
    for (int off = 32; off; off >>= 1) acc += __shfl_xor(acc, off);

    __shared__ float ws[4];
    if (lane == 0) ws[threadIdx.x >> 6] = acc;
    __syncthreads();
    if (threadIdx.x == 0) {
        float s = (ws[0] + ws[1]) + (ws[2] + ws[3]);
        partials[blockIdx.x] = s;
    }
}

// ---------------- kernel F: finalize loss ------------------------------------
__global__ __launch_bounds__(256) void finalize_kernel(const float* __restrict__ partials,
                                                       int nPart, float* __restrict__ lossOut,
                                                       float totalElems) {
    __shared__ float sh[256];
    float s = 0.0f;
    for (int i = threadIdx.x; i < nPart; i += 256) s += partials[i];
    sh[threadIdx.x] = s;
    __syncthreads();
    for (int stride = 128; stride; stride >>= 1) {
        if (threadIdx.x < stride) sh[threadIdx.x] += sh[threadIdx.x + stride];
        __syncthreads();
    }
    if (threadIdx.x == 0) {
        float m = sh[0] / totalElems;
        float p = 0.25f * m;
        lossOut[0] = __fadd_rn(p, m);
    }
}

extern "C" void kernel_launch(void* const* d_in, const int* in_sizes, int n_in,
                              void* d_out, int out_size, void* d_ws, size_t ws_size,
                              hipStream_t stream) {
    const float* z = (const float*)d_in[0];
    const float* cb = (const float*)d_in[1];
    const int N = in_sizes[0] / DD;   // 131072
    const int K = in_sizes[1] / DD;   // 1024

    float* out0 = (float*)d_out;                       // z_q_st
    float* lossOut = out0 + (size_t)N * DD;            // 1 float
    float* outIdxF = lossOut + 1;                      // N floats

    unsigned char* pack = (unsigned char*)d_ws;        // 256 KB
    unsigned* maxcn = (unsigned*)(pack + 16 * TILEB);  // [0]
    unsigned* cnt = maxcn + 1;                         // [1]
    float* cnorm = (float*)(maxcn + 2);                // K floats (np-exact)
    float* cnsb = cnorm + K;                           // K floats (biased-scaled)
    float* partials = cnsb + K;                        // 2048 floats
    unsigned* list = (unsigned*)(partials + 2048);     // N uints

    hipMemsetAsync(maxcn, 0, 8, stream);               // zero maxcn + cnt

    packc_kernel<<<32, 256, 0, stream>>>(cb, pack, cnorm, cnsb, maxcn, K);
    mfma_argmin_kernel<<<N / 256, 512, 0, stream>>>(z, pack, cnsb, maxcn,
                                                    outIdxF, cnt, list, N, K);
    refine_kernel<<<512, 256, 0, stream>>>(z, cb, cnorm, cnt, list, outIdxF, K);

    const int nBlocks2 = 2048;
    gather_kernel<<<nBlocks2, 256, 0, stream>>>(z, cb, outIdxF, out0, partials, N);
    finalize_kernel<<<1, 256, 0, stream>>>(partials, nBlocks2, lossOut,
                                           (float)((size_t)N * DD));
}